// Round 19
// baseline (319.628 us; speedup 1.0000x reference)
//
#include <hip/hip_runtime.h>
#include <hip/hip_bf16.h>

// SR-GNN session model, MI355X (gfx950). Inputs fp32/int32, output fp32.
// r19: EXACTLY r17 (313.2us baseline) with ONE change — score8 stores
// flipped nontemporal -> normal. Rationale: NV_OUT=49999 makes every output
// row misaligned (row base mod 128B = 60*b; odd rows 16B-misaligned), so
// each 1KB wave-store spans 7 full + 2 partial cache lines. Normal stores
// let L2 merge partial edge lines with the neighboring block's writes;
// nt pushes partials to HBM early -> RMW amplification (~192 vs 123 floor).
// r18's conv-merge and 512-col tiles were neutral -> reverted.
//
// ws: [0) unused 512KB | [512K) sg_hi 256KB | [768K) sg_lo 256KB
//     [1M) emb_b bf16 EMB_ROWS x 32 (3.07MB)

#define B_BATCH 4096
#define N_NODE  16
#define L_SEQ   20
#define D_DIM   32
#define NV_OUT  49999
#define EMB_ROWS 50176   // 196*256: last tile reach

typedef float  f32x4  __attribute__((ext_vector_type(4)));
typedef float  f32x4u __attribute__((ext_vector_type(4), aligned(4)));
typedef __bf16 bf16x8 __attribute__((ext_vector_type(8)));

__device__ __forceinline__ float sigf(float x) {
    return 1.0f / (1.0f + __expf(-x));
}

// ---------------------------------------------------------------- kernel 1
// session3v (r17 verbatim): f32x4 broadcast operand reads, fused hi/lo out.
__global__ __launch_bounds__(256) void session3_kernel(
    const int*   __restrict__ alias_inputs,  // [B,20]
    const float* __restrict__ A,             // [B,16,32]
    const int*   __restrict__ items,         // [B,16]
    const int*   __restrict__ mask,          // [B,20]
    const float* __restrict__ emb,           // [V,32]
    const float* __restrict__ w_ih,          // [96,64]
    const float* __restrict__ w_hh,          // [96,32]
    const float* __restrict__ b_ih, const float* __restrict__ b_hh,
    const float* __restrict__ b_iah, const float* __restrict__ b_oah,
    const float* __restrict__ w_ein, const float* __restrict__ b_ein,
    const float* __restrict__ w_eout, const float* __restrict__ b_eout,
    const float* __restrict__ w1, const float* __restrict__ b1,
    const float* __restrict__ w2, const float* __restrict__ b2,
    const float* __restrict__ w3,
    __hip_bfloat16* __restrict__ sg_hi,      // [B,32] (ws)
    __hip_bfloat16* __restrict__ sg_lo)      // [B,32] (ws)
{
    const int b   = blockIdx.x;
    const int tid = threadIdx.x;
    const int g   = tid >> 5;
    const int d   = tid & 31;
    const int n0  = g, n1 = g + 8;

    __shared__ float h_s [N_NODE][D_DIM];
    __shared__ float A_s [N_NODE][2 * N_NODE];
    __shared__ float ni_s[N_NODE][D_DIM];
    __shared__ float no_s[N_NODE][D_DIM];
    __shared__ float ii_s[N_NODE][D_DIM];
    __shared__ float io_s[N_NODE][D_DIM];
    __shared__ float wih_s[96][66];           // bank=(2d+k)%32 -> 2-way (free)
    __shared__ float whh_s[96][34];
    __shared__ float q1_s[D_DIM];
    __shared__ float alpha_s[L_SEQ];
    __shared__ int   last_s;

    for (int idx = tid; idx < 512; idx += 256) {
        const int n = idx >> 5, dd = idx & 31;
        const int it = items[b * N_NODE + n];
        h_s[n][dd] = emb[(size_t)it * D_DIM + dd];
        A_s[n][dd] = A[(size_t)b * 512 + idx];
    }
    for (int f = tid; f < 96 * 64; f += 256) wih_s[f >> 6][f & 63] = w_ih[f];
    for (int f = tid; f < 96 * 32; f += 256) whh_s[f >> 5][f & 31] = w_hh[f];
    __syncthreads();

    // ---- P1: node_in/node_out (h operands as f32x4 broadcast reads)
    float ai0 = b_ein[d], ao0 = b_eout[d];
    float ai1 = ai0,      ao1 = ao0;
    #pragma unroll
    for (int kb = 0; kb < 8; ++kb) {
        const int k0 = kb * 4;
        const f32x4 h0v = *reinterpret_cast<const f32x4*>(&h_s[n0][k0]);
        const f32x4 h1v = *reinterpret_cast<const f32x4*>(&h_s[n1][k0]);
        #pragma unroll
        for (int j = 0; j < 4; ++j) {
            const int k = k0 + j;
            const float we = w_ein[k * 32 + d], wo = w_eout[k * 32 + d];
            ai0 += h0v[j] * we; ai1 += h1v[j] * we;
            ao0 += h0v[j] * wo; ao1 += h1v[j] * wo;
        }
    }
    ni_s[n0][d] = ai0; ni_s[n1][d] = ai1;
    no_s[n0][d] = ao0; no_s[n1][d] = ao1;
    __syncthreads();

    // ---- P2: adjacency (A rows as f32x4 broadcast reads)
    float iv0 = b_iah[d], ov0 = b_oah[d];
    float iv1 = iv0,      ov1 = ov0;
    #pragma unroll
    for (int mb = 0; mb < 4; ++mb) {
        const int m0 = mb * 4;
        const f32x4 a0i = *reinterpret_cast<const f32x4*>(&A_s[n0][m0]);
        const f32x4 a1i = *reinterpret_cast<const f32x4*>(&A_s[n1][m0]);
        const f32x4 a0o = *reinterpret_cast<const f32x4*>(&A_s[n0][N_NODE + m0]);
        const f32x4 a1o = *reinterpret_cast<const f32x4*>(&A_s[n1][N_NODE + m0]);
        #pragma unroll
        for (int j = 0; j < 4; ++j) {
            const int m = m0 + j;
            const float nim = ni_s[m][d], nom = no_s[m][d];
            iv0 += a0i[j] * nim;
            iv1 += a1i[j] * nim;
            ov0 += a0o[j] * nom;
            ov1 += a1o[j] * nom;
        }
    }
    ii_s[n0][d] = iv0; ii_s[n1][d] = iv1;
    io_s[n0][d] = ov0; io_s[n1][d] = ov1;
    __syncthreads();

    // ---- P3 (fused gates): operands f32x4 broadcast; weights b32 (2-way free)
    float r0 = b_ih[d] + b_hh[d],           r1 = r0;
    float i0 = b_ih[32 + d] + b_hh[32 + d], i1 = i0;
    float gn0 = b_ih[64 + d],               gn1 = gn0;
    float hn0 = b_hh[64 + d],               hn1 = hn0;
    #pragma unroll
    for (int kb = 0; kb < 8; ++kb) {
        const int k0 = kb * 4;
        const f32x4 a0v = *reinterpret_cast<const f32x4*>(&ii_s[n0][k0]);
        const f32x4 a1v = *reinterpret_cast<const f32x4*>(&ii_s[n1][k0]);
        const f32x4 o0v = *reinterpret_cast<const f32x4*>(&io_s[n0][k0]);
        const f32x4 o1v = *reinterpret_cast<const f32x4*>(&io_s[n1][k0]);
        const f32x4 h0v = *reinterpret_cast<const f32x4*>(&h_s[n0][k0]);
        const f32x4 h1v = *reinterpret_cast<const f32x4*>(&h_s[n1][k0]);
        #pragma unroll
        for (int j = 0; j < 4; ++j) {
            const int k = k0 + j;
            const float wri = wih_s[d][k],      wro = wih_s[d][32 + k];
            const float wii = wih_s[32 + d][k], wio = wih_s[32 + d][32 + k];
            const float wni = wih_s[64 + d][k], wno = wih_s[64 + d][32 + k];
            const float whr = whh_s[d][k];
            const float whi = whh_s[32 + d][k];
            const float whn = whh_s[64 + d][k];
            r0  += a0v[j] * wri + o0v[j] * wro + h0v[j] * whr;
            r1  += a1v[j] * wri + o1v[j] * wro + h1v[j] * whr;
            i0  += a0v[j] * wii + o0v[j] * wio + h0v[j] * whi;
            i1  += a1v[j] * wii + o1v[j] * wio + h1v[j] * whi;
            gn0 += a0v[j] * wni + o0v[j] * wno;
            gn1 += a1v[j] * wni + o1v[j] * wno;
            hn0 += h0v[j] * whn;
            hn1 += h1v[j] * whn;
        }
    }

    float hv0, hv1;
    {
        const float rg0 = sigf(r0), ig0 = sigf(i0);
        const float x0  = gn0 + rg0 * hn0;
        const float e0  = __expf(2.0f * fabsf(x0));
        const float ng0 = copysignf(1.0f - 2.0f / (e0 + 1.0f), x0);
        hv0 = ng0 + ig0 * (h_s[n0][d] - ng0);
        const float rg1 = sigf(r1), ig1 = sigf(i1);
        const float x1  = gn1 + rg1 * hn1;
        const float e1  = __expf(2.0f * fabsf(x1));
        const float ng1 = copysignf(1.0f - 2.0f / (e1 + 1.0f), x1);
        hv1 = ng1 + ig1 * (h_s[n1][d] - ng1);
    }
    __syncthreads();
    h_s[n0][d] = hv0;
    h_s[n1][d] = hv1;
    __syncthreads();

    for (int idx = tid; idx < L_SEQ * D_DIM; idx += 256) {
        const int t = idx >> 5, dd = idx & 31;
        const int a = alias_inputs[b * L_SEQ + t];
        const float v = h_s[a][dd];
        if (t < 16) ni_s[t][dd] = v;
        else        no_s[t - 16][dd] = v;
    }
    if (tid == 0) {
        int s = 0;
        for (int t = 0; t < L_SEQ; ++t) s += mask[b * L_SEQ + t];
        last_s = s - 1;
    }
    __syncthreads();

    if (tid < D_DIM) {
        const int lt = last_s;
        const float* sl = (lt < 16) ? &ni_s[lt][0] : &no_s[lt - 16][0];
        float acc = b1[tid];
        #pragma unroll
        for (int k = 0; k < 32; ++k) acc += sl[k] * w1[k * 32 + tid];
        q1_s[tid] = acc;
    }
    __syncthreads();

    for (int idx = tid; idx < L_SEQ * D_DIM; idx += 256) {
        const int t = idx >> 5, dd = idx & 31;
        const float* sp = (t < 16) ? &ni_s[t][0] : &no_s[t - 16][0];
        float q2 = b2[dd];
        #pragma unroll
        for (int k = 0; k < 32; ++k) q2 += sp[k] * w2[k * 32 + dd];
        const float val = sigf(q1_s[dd] + q2) * w3[dd];
        if (t < 16) ii_s[t][dd] = val;
        else        io_s[t - 16][dd] = val;
    }
    __syncthreads();
    if (tid < L_SEQ) {
        const float* tp = (tid < 16) ? &ii_s[tid][0] : &io_s[tid - 16][0];
        float a = 0.0f;
        #pragma unroll
        for (int dd = 0; dd < 32; ++dd) a += tp[dd];
        alpha_s[tid] = a * (float)mask[b * L_SEQ + tid];
    }
    __syncthreads();

    // ---- P8: s_g -> hi/lo bf16 split (fused)
    if (tid < D_DIM) {
        float acc = 0.0f;
        #pragma unroll
        for (int t = 0; t < L_SEQ; ++t) {
            const float sv = (t < 16) ? ni_s[t][tid] : no_s[t - 16][tid];
            acc += alpha_s[t] * sv;
        }
        const __hip_bfloat16 h = __float2bfloat16(acc);
        sg_hi[b * D_DIM + tid] = h;
        sg_lo[b * D_DIM + tid] = __float2bfloat16(acc - __bfloat162float(h));
    }
}

// ---------------------------------------------------------------- kernel C1
__global__ __launch_bounds__(256) void conv_emb_kernel(
    const float* __restrict__ emb, __hip_bfloat16* __restrict__ emb_b)
{
    const int total = EMB_ROWS * D_DIM;
    for (int i = blockIdx.x * 256 + threadIdx.x; i < total; i += gridDim.x * 256) {
        const int v = i >> 5, k = i & 31;
        int src = v + 1;
        if (src > NV_OUT) src = NV_OUT;
        emb_b[i] = __float2bfloat16(emb[(size_t)src * D_DIM + k]);
    }
}

// ---------------------------------------------------------------- kernel 2
// score8n: r15/r17 score8 with NORMAL stores (the single variable).
// 16-row tile (8 blocks/CU), LDS-staged output, contiguous 1KB dwordx4.
// Grid: (196 v-tiles, 256 b-tiles).
__global__ __launch_bounds__(256) void score8_kernel(
    const __hip_bfloat16* __restrict__ sg_hi,  // [4096,32]
    const __hip_bfloat16* __restrict__ sg_lo,  // [4096,32]
    const __hip_bfloat16* __restrict__ emb_b,  // [EMB_ROWS,32]
    float* __restrict__ out)                   // [4096,49999] f32
{
    __shared__ float T[16][260];               // 16.6 KB
    const int wave = threadIdx.x >> 6;
    const int lane = threadIdx.x & 63;
    const int rc   = lane & 15;
    const int kgrp = lane >> 4;
    const int b0   = blockIdx.y * 16;
    const int v0   = blockIdx.x * 256;
    const int vw   = v0 + wave * 64;

    const bf16x8 ah = *reinterpret_cast<const bf16x8*>(
        &sg_hi[(size_t)(b0 + rc) * D_DIM + kgrp * 8]);
    const bf16x8 al = *reinterpret_cast<const bf16x8*>(
        &sg_lo[(size_t)(b0 + rc) * D_DIM + kgrp * 8]);

    #pragma unroll
    for (int s = 0; s < 4; ++s) {
        const int vt = vw + s * 16;
        const bf16x8 bf = *reinterpret_cast<const bf16x8*>(
            &emb_b[(size_t)(vt + rc) * D_DIM + kgrp * 8]);
        f32x4 acc = {0.0f, 0.0f, 0.0f, 0.0f};
        acc = __builtin_amdgcn_mfma_f32_16x16x32_bf16(ah, bf, acc, 0, 0, 0);
        acc = __builtin_amdgcn_mfma_f32_16x16x32_bf16(al, bf, acc, 0, 0, 0);
        const int col = wave * 64 + s * 16 + rc;
        #pragma unroll
        for (int j = 0; j < 4; ++j)
            T[kgrp * 4 + j][col] = acc[j];
    }
    __syncthreads();

    if (v0 + 256 <= NV_OUT) {
        #pragma unroll
        for (int r = 0; r < 4; ++r) {
            const int row = wave * 4 + r;
            const f32x4 val = *reinterpret_cast<const f32x4*>(&T[row][lane * 4]);
            *reinterpret_cast<f32x4u*>(
                &out[(size_t)(b0 + row) * NV_OUT + v0 + lane * 4]) = val;  // normal
        }
    } else {
        #pragma unroll
        for (int r = 0; r < 4; ++r) {
            const int row = wave * 4 + r;
            float* op = &out[(size_t)(b0 + row) * NV_OUT];
            #pragma unroll
            for (int j = 0; j < 4; ++j) {
                const int c = lane * 4 + j;
                if (v0 + c < NV_OUT) op[v0 + c] = T[row][c];
            }
        }
    }
}

// ---------------------------------------------------------------- launch
extern "C" void kernel_launch(void* const* d_in, const int* in_sizes, int n_in,
                              void* d_out, int out_size, void* d_ws, size_t ws_size,
                              hipStream_t stream)
{
    const int*   alias_inputs = (const int*)  d_in[0];
    const float* A      = (const float*)d_in[1];
    const int*   items  = (const int*)  d_in[2];
    const int*   mask   = (const int*)  d_in[3];
    const float* emb    = (const float*)d_in[4];
    const float* w_ih   = (const float*)d_in[5];
    const float* w_hh   = (const float*)d_in[6];
    const float* b_ih   = (const float*)d_in[7];
    const float* b_hh   = (const float*)d_in[8];
    const float* b_iah  = (const float*)d_in[9];
    const float* b_oah  = (const float*)d_in[10];
    const float* w_ein  = (const float*)d_in[11];
    const float* b_ein  = (const float*)d_in[12];
    const float* w_eout = (const float*)d_in[13];
    const float* b_eout = (const float*)d_in[14];
    const float* w1     = (const float*)d_in[15];
    const float* b1     = (const float*)d_in[16];
    const float* w2     = (const float*)d_in[17];
    const float* b2     = (const float*)d_in[18];
    const float* w3     = (const float*)d_in[19];

    __hip_bfloat16* sg_hi = (__hip_bfloat16*)((char*)d_ws + 512 * 1024);
    __hip_bfloat16* sg_lo = (__hip_bfloat16*)((char*)d_ws + 768 * 1024);
    __hip_bfloat16* emb_b = (__hip_bfloat16*)((char*)d_ws + 1024 * 1024);
    float* out = (float*)d_out;

    hipLaunchKernelGGL(conv_emb_kernel, dim3(2048), dim3(256), 0, stream,
                       emb, emb_b);

    hipLaunchKernelGGL(session3_kernel, dim3(B_BATCH), dim3(256), 0, stream,
                       alias_inputs, A, items, mask, emb,
                       w_ih, w_hh, b_ih, b_hh, b_iah, b_oah,
                       w_ein, b_ein, w_eout, b_eout,
                       w1, b1, w2, b2, w3, sg_hi, sg_lo);

    hipLaunchKernelGGL(score8_kernel,
                       dim3((NV_OUT + 255) / 256, B_BATCH / 16),
                       dim3(256), 0, stream, sg_hi, sg_lo, emb_b, out);
}

// Round 20
// 306.935 us; speedup vs baseline: 1.0414x; 1.0414x over previous
//
#include <hip/hip_runtime.h>
#include <hip/hip_bf16.h>

// SR-GNN session model, MI355X (gfx950). Inputs fp32/int32, output fp32.
// r20: session occupancy fix. r17 session was latency-bound at 3 blocks/CU
// (49.8KB LDS, 38KB of it weight staging). Weights now TRANSPOSED once into
// ws (2 extra conv blocks); P3 reads w_ihT[k*96+d] = coalesced 128B wave
// loads (the proven P1 pattern). LDS 49.8->12.2KB => 8 blocks/CU (wave cap),
// no per-block weight staging. Score8 = r17 verbatim (nt stores; best 313.2;
// normal stores r19 = null). Conv kernel verbatim + 2 transpose blocks.
//
// ws: [0) w_ihT 24KB | [24K) w_hhT 12KB | [512K) sg_hi 256KB
//     [768K) sg_lo 256KB | [1M) emb_b bf16 EMB_ROWS x 32 (3.07MB)

#define B_BATCH 4096
#define N_NODE  16
#define L_SEQ   20
#define D_DIM   32
#define NV_OUT  49999
#define EMB_ROWS 50176   // 196*256: last tile reach
#define CONV_GRID 2050   // 2048 emb-convert + 2 weight-transpose

typedef float  f32x4  __attribute__((ext_vector_type(4)));
typedef float  f32x4u __attribute__((ext_vector_type(4), aligned(4)));
typedef __bf16 bf16x8 __attribute__((ext_vector_type(8)));

__device__ __forceinline__ float sigf(float x) {
    return 1.0f / (1.0f + __expf(-x));
}

// ---------------------------------------------------------------- kernel 1
// session4: 12.2KB LDS (8 blocks/CU); weights read coalesced from w_ihT/w_hhT.
__global__ __launch_bounds__(256) void session4_kernel(
    const int*   __restrict__ alias_inputs,  // [B,20]
    const float* __restrict__ A,             // [B,16,32]
    const int*   __restrict__ items,         // [B,16]
    const int*   __restrict__ mask,          // [B,20]
    const float* __restrict__ emb,           // [V,32]
    const float* __restrict__ w_ihT,         // [64,96] (ws, transposed)
    const float* __restrict__ w_hhT,         // [32,96] (ws, transposed)
    const float* __restrict__ b_ih, const float* __restrict__ b_hh,
    const float* __restrict__ b_iah, const float* __restrict__ b_oah,
    const float* __restrict__ w_ein, const float* __restrict__ b_ein,
    const float* __restrict__ w_eout, const float* __restrict__ b_eout,
    const float* __restrict__ w1, const float* __restrict__ b1,
    const float* __restrict__ w2, const float* __restrict__ b2,
    const float* __restrict__ w3,
    __hip_bfloat16* __restrict__ sg_hi,      // [B,32] (ws)
    __hip_bfloat16* __restrict__ sg_lo)      // [B,32] (ws)
{
    const int b   = blockIdx.x;
    const int tid = threadIdx.x;
    const int g   = tid >> 5;
    const int d   = tid & 31;
    const int n0  = g, n1 = g + 8;

    __shared__ float h_s [N_NODE][D_DIM];
    __shared__ float A_s [N_NODE][2 * N_NODE];
    __shared__ float ni_s[N_NODE][D_DIM];
    __shared__ float no_s[N_NODE][D_DIM];
    __shared__ float ii_s[N_NODE][D_DIM];
    __shared__ float io_s[N_NODE][D_DIM];
    __shared__ float q1_s[D_DIM];
    __shared__ float alpha_s[L_SEQ];
    __shared__ int   last_s;                 // ~12.2 KB total

    for (int idx = tid; idx < 512; idx += 256) {
        const int n = idx >> 5, dd = idx & 31;
        const int it = items[b * N_NODE + n];
        h_s[n][dd] = emb[(size_t)it * D_DIM + dd];
        A_s[n][dd] = A[(size_t)b * 512 + idx];
    }
    __syncthreads();

    // ---- P1: node_in/node_out (h operands as f32x4 broadcast reads)
    float ai0 = b_ein[d], ao0 = b_eout[d];
    float ai1 = ai0,      ao1 = ao0;
    #pragma unroll
    for (int kb = 0; kb < 8; ++kb) {
        const int k0 = kb * 4;
        const f32x4 h0v = *reinterpret_cast<const f32x4*>(&h_s[n0][k0]);
        const f32x4 h1v = *reinterpret_cast<const f32x4*>(&h_s[n1][k0]);
        #pragma unroll
        for (int j = 0; j < 4; ++j) {
            const int k = k0 + j;
            const float we = w_ein[k * 32 + d], wo = w_eout[k * 32 + d];
            ai0 += h0v[j] * we; ai1 += h1v[j] * we;
            ao0 += h0v[j] * wo; ao1 += h1v[j] * wo;
        }
    }
    ni_s[n0][d] = ai0; ni_s[n1][d] = ai1;
    no_s[n0][d] = ao0; no_s[n1][d] = ao1;
    __syncthreads();

    // ---- P2: adjacency (A rows as f32x4 broadcast reads)
    float iv0 = b_iah[d], ov0 = b_oah[d];
    float iv1 = iv0,      ov1 = ov0;
    #pragma unroll
    for (int mb = 0; mb < 4; ++mb) {
        const int m0 = mb * 4;
        const f32x4 a0i = *reinterpret_cast<const f32x4*>(&A_s[n0][m0]);
        const f32x4 a1i = *reinterpret_cast<const f32x4*>(&A_s[n1][m0]);
        const f32x4 a0o = *reinterpret_cast<const f32x4*>(&A_s[n0][N_NODE + m0]);
        const f32x4 a1o = *reinterpret_cast<const f32x4*>(&A_s[n1][N_NODE + m0]);
        #pragma unroll
        for (int j = 0; j < 4; ++j) {
            const int m = m0 + j;
            const float nim = ni_s[m][d], nom = no_s[m][d];
            iv0 += a0i[j] * nim;
            iv1 += a1i[j] * nim;
            ov0 += a0o[j] * nom;
            ov1 += a1o[j] * nom;
        }
    }
    ii_s[n0][d] = iv0; ii_s[n1][d] = iv1;
    io_s[n0][d] = ov0; io_s[n1][d] = ov1;
    __syncthreads();

    // ---- P3 (fused gates): weights via coalesced transposed-global reads
    float r0 = b_ih[d] + b_hh[d],           r1 = r0;
    float i0 = b_ih[32 + d] + b_hh[32 + d], i1 = i0;
    float gn0 = b_ih[64 + d],               gn1 = gn0;
    float hn0 = b_hh[64 + d],               hn1 = hn0;
    #pragma unroll
    for (int kb = 0; kb < 8; ++kb) {
        const int k0 = kb * 4;
        const f32x4 a0v = *reinterpret_cast<const f32x4*>(&ii_s[n0][k0]);
        const f32x4 a1v = *reinterpret_cast<const f32x4*>(&ii_s[n1][k0]);
        const f32x4 o0v = *reinterpret_cast<const f32x4*>(&io_s[n0][k0]);
        const f32x4 o1v = *reinterpret_cast<const f32x4*>(&io_s[n1][k0]);
        const f32x4 h0v = *reinterpret_cast<const f32x4*>(&h_s[n0][k0]);
        const f32x4 h1v = *reinterpret_cast<const f32x4*>(&h_s[n1][k0]);
        #pragma unroll
        for (int j = 0; j < 4; ++j) {
            const int k = k0 + j;
            // w_ih[d][k] = w_ihT[k*96+d]; w_ih[d][32+k] = w_ihT[(32+k)*96+d]
            const float wri = w_ihT[k * 96 + d];
            const float wro = w_ihT[(32 + k) * 96 + d];
            const float wii = w_ihT[k * 96 + 32 + d];
            const float wio = w_ihT[(32 + k) * 96 + 32 + d];
            const float wni = w_ihT[k * 96 + 64 + d];
            const float wno = w_ihT[(32 + k) * 96 + 64 + d];
            const float whr = w_hhT[k * 96 + d];
            const float whi = w_hhT[k * 96 + 32 + d];
            const float whn = w_hhT[k * 96 + 64 + d];
            r0  += a0v[j] * wri + o0v[j] * wro + h0v[j] * whr;
            r1  += a1v[j] * wri + o1v[j] * wro + h1v[j] * whr;
            i0  += a0v[j] * wii + o0v[j] * wio + h0v[j] * whi;
            i1  += a1v[j] * wii + o1v[j] * wio + h1v[j] * whi;
            gn0 += a0v[j] * wni + o0v[j] * wno;
            gn1 += a1v[j] * wni + o1v[j] * wno;
            hn0 += h0v[j] * whn;
            hn1 += h1v[j] * whn;
        }
    }

    float hv0, hv1;
    {
        const float rg0 = sigf(r0), ig0 = sigf(i0);
        const float x0  = gn0 + rg0 * hn0;
        const float e0  = __expf(2.0f * fabsf(x0));
        const float ng0 = copysignf(1.0f - 2.0f / (e0 + 1.0f), x0);
        hv0 = ng0 + ig0 * (h_s[n0][d] - ng0);
        const float rg1 = sigf(r1), ig1 = sigf(i1);
        const float x1  = gn1 + rg1 * hn1;
        const float e1  = __expf(2.0f * fabsf(x1));
        const float ng1 = copysignf(1.0f - 2.0f / (e1 + 1.0f), x1);
        hv1 = ng1 + ig1 * (h_s[n1][d] - ng1);
    }
    __syncthreads();
    h_s[n0][d] = hv0;
    h_s[n1][d] = hv1;
    __syncthreads();

    for (int idx = tid; idx < L_SEQ * D_DIM; idx += 256) {
        const int t = idx >> 5, dd = idx & 31;
        const int a = alias_inputs[b * L_SEQ + t];
        const float v = h_s[a][dd];
        if (t < 16) ni_s[t][dd] = v;
        else        no_s[t - 16][dd] = v;
    }
    if (tid == 0) {
        int s = 0;
        for (int t = 0; t < L_SEQ; ++t) s += mask[b * L_SEQ + t];
        last_s = s - 1;
    }
    __syncthreads();

    if (tid < D_DIM) {
        const int lt = last_s;
        const float* sl = (lt < 16) ? &ni_s[lt][0] : &no_s[lt - 16][0];
        float acc = b1[tid];
        #pragma unroll
        for (int k = 0; k < 32; ++k) acc += sl[k] * w1[k * 32 + tid];
        q1_s[tid] = acc;
    }
    __syncthreads();

    for (int idx = tid; idx < L_SEQ * D_DIM; idx += 256) {
        const int t = idx >> 5, dd = idx & 31;
        const float* sp = (t < 16) ? &ni_s[t][0] : &no_s[t - 16][0];
        float q2 = b2[dd];
        #pragma unroll
        for (int k = 0; k < 32; ++k) q2 += sp[k] * w2[k * 32 + dd];
        const float val = sigf(q1_s[dd] + q2) * w3[dd];
        if (t < 16) ii_s[t][dd] = val;
        else        io_s[t - 16][dd] = val;
    }
    __syncthreads();
    if (tid < L_SEQ) {
        const float* tp = (tid < 16) ? &ii_s[tid][0] : &io_s[tid - 16][0];
        float a = 0.0f;
        #pragma unroll
        for (int dd = 0; dd < 32; ++dd) a += tp[dd];
        alpha_s[tid] = a * (float)mask[b * L_SEQ + tid];
    }
    __syncthreads();

    // ---- P8: s_g -> hi/lo bf16 split (fused)
    if (tid < D_DIM) {
        float acc = 0.0f;
        #pragma unroll
        for (int t = 0; t < L_SEQ; ++t) {
            const float sv = (t < 16) ? ni_s[t][tid] : no_s[t - 16][tid];
            acc += alpha_s[t] * sv;
        }
        const __hip_bfloat16 h = __float2bfloat16(acc);
        sg_hi[b * D_DIM + tid] = h;
        sg_lo[b * D_DIM + tid] = __float2bfloat16(acc - __bfloat162float(h));
    }
}

// ---------------------------------------------------------------- kernel C1
// blocks [0,2048): emb fp32->bf16; block 2048: w_ih transpose; 2049: w_hh.
__global__ __launch_bounds__(256) void conv_prep_kernel(
    const float* __restrict__ emb, __hip_bfloat16* __restrict__ emb_b,
    const float* __restrict__ w_ih, const float* __restrict__ w_hh,
    float* __restrict__ w_ihT, float* __restrict__ w_hhT)
{
    const int tid = threadIdx.x;
    if (blockIdx.x == 2048) {
        for (int i = tid; i < 64 * 96; i += 256) {
            const int k = i / 96, j = i % 96;
            w_ihT[i] = w_ih[j * 64 + k];
        }
        return;
    }
    if (blockIdx.x == 2049) {
        for (int i = tid; i < 32 * 96; i += 256) {
            const int k = i / 96, j = i % 96;
            w_hhT[i] = w_hh[j * 32 + k];
        }
        return;
    }
    const int total = EMB_ROWS * D_DIM;
    for (int i = blockIdx.x * 256 + tid; i < total; i += 2048 * 256) {
        const int v = i >> 5, k = i & 31;
        int src = v + 1;
        if (src > NV_OUT) src = NV_OUT;
        emb_b[i] = __float2bfloat16(emb[(size_t)src * D_DIM + k]);
    }
}

// ---------------------------------------------------------------- kernel 2
// VERBATIM r17 score8: 16-row tile, LDS-staged output, contiguous 1KB
// dwordx4 NONTEMPORAL stores. Grid: (196 v-tiles, 256 b-tiles).
__global__ __launch_bounds__(256) void score8_kernel(
    const __hip_bfloat16* __restrict__ sg_hi,  // [4096,32]
    const __hip_bfloat16* __restrict__ sg_lo,  // [4096,32]
    const __hip_bfloat16* __restrict__ emb_b,  // [EMB_ROWS,32]
    float* __restrict__ out)                   // [4096,49999] f32
{
    __shared__ float T[16][260];               // 16.6 KB
    const int wave = threadIdx.x >> 6;
    const int lane = threadIdx.x & 63;
    const int rc   = lane & 15;
    const int kgrp = lane >> 4;
    const int b0   = blockIdx.y * 16;
    const int v0   = blockIdx.x * 256;
    const int vw   = v0 + wave * 64;

    const bf16x8 ah = *reinterpret_cast<const bf16x8*>(
        &sg_hi[(size_t)(b0 + rc) * D_DIM + kgrp * 8]);
    const bf16x8 al = *reinterpret_cast<const bf16x8*>(
        &sg_lo[(size_t)(b0 + rc) * D_DIM + kgrp * 8]);

    #pragma unroll
    for (int s = 0; s < 4; ++s) {
        const int vt = vw + s * 16;
        const bf16x8 bf = *reinterpret_cast<const bf16x8*>(
            &emb_b[(size_t)(vt + rc) * D_DIM + kgrp * 8]);
        f32x4 acc = {0.0f, 0.0f, 0.0f, 0.0f};
        acc = __builtin_amdgcn_mfma_f32_16x16x32_bf16(ah, bf, acc, 0, 0, 0);
        acc = __builtin_amdgcn_mfma_f32_16x16x32_bf16(al, bf, acc, 0, 0, 0);
        const int col = wave * 64 + s * 16 + rc;
        #pragma unroll
        for (int j = 0; j < 4; ++j)
            T[kgrp * 4 + j][col] = acc[j];
    }
    __syncthreads();

    if (v0 + 256 <= NV_OUT) {
        #pragma unroll
        for (int r = 0; r < 4; ++r) {
            const int row = wave * 4 + r;
            const f32x4 val = *reinterpret_cast<const f32x4*>(&T[row][lane * 4]);
            f32x4u* op = reinterpret_cast<f32x4u*>(
                &out[(size_t)(b0 + row) * NV_OUT + v0 + lane * 4]);
            __builtin_nontemporal_store(val, op);
        }
    } else {
        #pragma unroll
        for (int r = 0; r < 4; ++r) {
            const int row = wave * 4 + r;
            float* op = &out[(size_t)(b0 + row) * NV_OUT];
            #pragma unroll
            for (int j = 0; j < 4; ++j) {
                const int c = lane * 4 + j;
                if (v0 + c < NV_OUT) op[v0 + c] = T[row][c];
            }
        }
    }
}

// ---------------------------------------------------------------- launch
extern "C" void kernel_launch(void* const* d_in, const int* in_sizes, int n_in,
                              void* d_out, int out_size, void* d_ws, size_t ws_size,
                              hipStream_t stream)
{
    const int*   alias_inputs = (const int*)  d_in[0];
    const float* A      = (const float*)d_in[1];
    const int*   items  = (const int*)  d_in[2];
    const int*   mask   = (const int*)  d_in[3];
    const float* emb    = (const float*)d_in[4];
    const float* w_ih   = (const float*)d_in[5];
    const float* w_hh   = (const float*)d_in[6];
    const float* b_ih   = (const float*)d_in[7];
    const float* b_hh   = (const float*)d_in[8];
    const float* b_iah  = (const float*)d_in[9];
    const float* b_oah  = (const float*)d_in[10];
    const float* w_ein  = (const float*)d_in[11];
    const float* b_ein  = (const float*)d_in[12];
    const float* w_eout = (const float*)d_in[13];
    const float* b_eout = (const float*)d_in[14];
    const float* w1     = (const float*)d_in[15];
    const float* b1     = (const float*)d_in[16];
    const float* w2     = (const float*)d_in[17];
    const float* b2     = (const float*)d_in[18];
    const float* w3     = (const float*)d_in[19];

    float* w_ihT = (float*)d_ws;                                    // 24 KB
    float* w_hhT = (float*)((char*)d_ws + 24576);                   // 12 KB
    __hip_bfloat16* sg_hi = (__hip_bfloat16*)((char*)d_ws + 512 * 1024);
    __hip_bfloat16* sg_lo = (__hip_bfloat16*)((char*)d_ws + 768 * 1024);
    __hip_bfloat16* emb_b = (__hip_bfloat16*)((char*)d_ws + 1024 * 1024);
    float* out = (float*)d_out;

    hipLaunchKernelGGL(conv_prep_kernel, dim3(CONV_GRID), dim3(256), 0, stream,
                       emb, emb_b, w_ih, w_hh, w_ihT, w_hhT);

    hipLaunchKernelGGL(session4_kernel, dim3(B_BATCH), dim3(256), 0, stream,
                       alias_inputs, A, items, mask, emb,
                       w_ihT, w_hhT, b_ih, b_hh, b_iah, b_oah,
                       w_ein, b_ein, w_eout, b_eout,
                       w1, b1, w2, b2, w3, sg_hi, sg_lo);

    hipLaunchKernelGGL(score8_kernel,
                       dim3((NV_OUT + 255) / 256, B_BATCH / 16),
                       dim3(256), 0, stream, sg_hi, sg_lo, emb_b, out);
}